// Round 3
// baseline (2433.676 us; speedup 1.0000x reference)
//
#include <hip/hip_runtime.h>
#include <math.h>

#define K 20
#define KP1 21
#define F 32
#define NNODES 1000000

#define NP1 112896   // 5376*21
#define NP2 5376     // 256*21
#define NP3 256

// ws float offsets
#define OFF_WQT  0
#define OFF_WVT  12288
#define OFF_WOT  24576
#define OFF_MW1T 36864
#define OFF_MW2T 46080
#define OFF_H1   49152
#define OFF_H2   (OFF_H1 + 2 * NP1 * F)
#define OFF_H3   (OFF_H2 + 2 * NP2 * F)

__device__ __forceinline__ int nhash(int node, int j) {
    return (node * 101 + (j + 1) * 7919) % NNODES;   // max ~1.01e8, fits int32
}

__global__ __launch_bounds__(256) void transpose_weights(
    const float* __restrict__ Wq, const float* __restrict__ Wv,
    const float* __restrict__ Wo, const float* __restrict__ mw1,
    const float* __restrict__ mw2, float* __restrict__ ws)
{
    const int l = blockIdx.x;            // 0..2
    const int tid = threadIdx.x;
    float* wqt  = ws + OFF_WQT  + l * 4096;
    float* wvt  = ws + OFF_WVT  + l * 4096;
    float* wot  = ws + OFF_WOT  + l * 4096;
    float* mw1t = ws + OFF_MW1T + l * 3072;
    float* mw2t = ws + OFF_MW2T + l * 1024;
    for (int i = tid; i < 4096; i += 256) {
        int d = i >> 6, e = i & 63;
        wqt[d * 64 + e] = Wq[l * 4096 + e * 64 + d];
        wvt[d * 64 + e] = Wv[l * 4096 + e * 64 + d];
        wot[d * 64 + e] = Wo[l * 4096 + e * 64 + d];
    }
    for (int i = tid; i < 3072; i += 256) {
        int d = i / 96, e = i % 96;
        mw1t[d * 96 + e] = mw1[l * 3072 + e * 32 + d];
    }
    for (int i = tid; i < 1024; i += 256) {
        int d = i >> 5, e = i & 31;
        mw2t[d * 32 + e] = mw2[l * 1024 + e * 32 + d];
    }
}

template<int LEVEL>
__global__ __launch_bounds__(256) void attn_kernel(
    const int* __restrict__ src_idx, const int* __restrict__ tgt_idx,
    const float* __restrict__ cut_time,
    const float* __restrict__ emb,
    const float* __restrict__ freq, const float* __restrict__ phase,
    const float* __restrict__ Wk_,     // original row-major [l][e][d]
    const float* __restrict__ WqT_, const float* __restrict__ WvT_,
    const float* __restrict__ WoT_,
    const float* __restrict__ mw1T_, const float* __restrict__ mb1_,
    const float* __restrict__ mw2T_, const float* __restrict__ mb2_,
    const float* __restrict__ h_in,
    float* __restrict__ h_out)
{
    constexpr int NPAIRS = (LEVEL == 1) ? NP1 : (LEVEL == 2 ? NP2 : NP3);
    constexpr int PREVN  = (LEVEL == 2) ? NP1 : NP2;
    constexpr int l = LEVEL - 1;
    constexpr int NBT = NPAIRS;          // batches of 2 pairs: 2*NPAIRS/2

    __shared__ float kin[4][2][K][64];
    __shared__ float qin[4][2][64];
    __shared__ float qz [4][2][4][68];   // qk -> z -> (flat alias) merge concat buf
    __shared__ float xb [4][2][64];      // qd -> od -> h(merge hidden)

    const int tid  = threadIdx.x;
    const int w    = tid >> 6;
    const int lane = tid & 63;
    const int h    = lane >> 4;
    const int c    = lane & 15;
    const int td   = lane & 31;
    const int half = lane >> 5;
    const int wof  = lane * 64;

    const float fr = freq[td], ph = phase[td];
    // q time-encoding is pair-invariant: cos(0*f + ph). Write once, persists.
    if (lane >= 32) {
        float qt = cosf(ph);
        qin[w][0][32 + td] = qt;
        qin[w][1][32 + td] = qt;
    }

    const float* Wk   = Wk_   + l * 4096;
    const float* WqT  = WqT_  + l * 4096;
    const float* WvT  = WvT_  + l * 4096;
    const float* WoT  = WoT_  + l * 4096;
    const float* mw1T = mw1T_ + l * 3072;
    const float* mb1  = mb1_  + l * 32;
    const float* mw2T = mw2T_ + l * 1024;
    const float* mb2  = mb2_  + l * 32;

    const int gstride = gridDim.x * 4;
    int g0 = blockIdx.x * 4 + w;

    float4 pf[2][3];
    int    na[2];
    float  ta[2];

    auto PREFETCH = [&](int gg) {
        #pragma unroll
        for (int q = 0; q < 2; ++q) {
            const int i    = gg * 2 + q;
            const int side = (i >= NPAIRS) ? 1 : 0;
            const int p    = i - side * NPAIRS;
            int b, s2 = 0, r = 0;
            if (LEVEL == 3)      { b = p; }
            else if (LEVEL == 2) { b = p / KP1; s2 = p % KP1; }
            else                 { int qq = p / KP1; r = p % KP1; b = qq / KP1; s2 = qq % KP1; }
            const int   root = side ? tgt_idx[b] : src_idx[b];
            const float ct   = cut_time[b];
            int nodeA; float tA;
            if (LEVEL == 3) { nodeA = root; tA = ct; }
            else if (LEVEL == 2) {
                nodeA = s2 ? nhash(root, s2 - 1) : root;
                tA    = s2 ? ct * ((float)s2 / 21.0f) : ct;
            } else {
                const int   node2 = s2 ? nhash(root, s2 - 1) : root;
                const float t2    = s2 ? ct * ((float)s2 / 21.0f) : ct;
                nodeA = r ? nhash(node2, r - 1) : node2;
                tA    = r ? t2 * ((float)r / 21.0f) : t2;
            }
            na[q] = nodeA; ta[q] = tA;
            if (LEVEL == 1) {
                #pragma unroll
                for (int it = 0; it < 3; ++it) {
                    const int idx4 = it * 64 + lane;
                    if (idx4 < 168) {
                        const int row = idx4 >> 3, c4 = idx4 & 7;
                        const int node = (row == 0) ? nodeA : nhash(nodeA, row - 1);
                        pf[q][it] = *(const float4*)&emb[(size_t)node * F + c4 * 4];
                    }
                }
            } else {
                const float* base = h_in + ((size_t)side * PREVN + (size_t)p * KP1) * F;
                #pragma unroll
                for (int it = 0; it < 3; ++it) {
                    const int idx4 = it * 64 + lane;
                    if (idx4 < 168) pf[q][it] = *(const float4*)&base[idx4 * 4];
                }
            }
        }
    };

    if (g0 < NBT) PREFETCH(g0);

    for (int g = g0; g < NBT; g += gstride) {
        // ---- 1. LDS fill from prefetched regs
        #pragma unroll
        for (int q = 0; q < 2; ++q) {
            #pragma unroll
            for (int it = 0; it < 3; ++it) {
                const int idx4 = it * 64 + lane;
                if (idx4 < 168) {
                    const int row = idx4 >> 3, c4 = idx4 & 7;
                    if (row == 0) *(float4*)&qin[w][q][c4 * 4]           = pf[q][it];
                    else          *(float4*)&kin[w][q][row - 1][c4 * 4]  = pf[q][it];
                }
            }
        }

        // ---- 2. time encodings + mask bits (uses na/ta of current batch)
        unsigned mb[2];
        #pragma unroll
        for (int q = 0; q < 2; ++q) {
            const float tA = ta[q];
            #pragma unroll
            for (int it = 0; it < 10; ++it) {
                const int j = it * 2 + half;
                const float ngh_t = tA * ((float)(j + 1) / 21.0f);
                const float delta = tA - ngh_t;
                kin[w][q][j][32 + td] = cosf(delta * fr + ph);
            }
            int m = (na[q] * 101 + 7919) % NNODES;   // nhash(na,0)
            unsigned bits = 0;
            #pragma unroll
            for (int j = 0; j < K; ++j) {
                if (m == 0) bits |= (1u << j);
                m += 7919; if (m >= NNODES) m -= NNODES;
            }
            mb[q] = bits;
        }

        const int gs = g;
        // ---- 3. prefetch next batch (loads fly under the compute below)
        if (g + gstride < NBT) PREFETCH(g + gstride);

        // ---- 4. q projection (batched)
        float qd0 = 0.f, qd1 = 0.f;
        #pragma unroll
        for (int e4 = 0; e4 < 16; ++e4) {
            const float4 w4 = *(const float4*)&WqT[wof + e4 * 4];
            const float4 x0 = *(float4*)&qin[w][0][e4 * 4];
            const float4 x1 = *(float4*)&qin[w][1][e4 * 4];
            qd0 += x0.x*w4.x + x0.y*w4.y + x0.z*w4.z + x0.w*w4.w;
            qd1 += x1.x*w4.x + x1.y*w4.y + x1.z*w4.z + x1.w*w4.w;
        }
        xb[w][0][lane] = qd0;
        xb[w][1][lane] = qd1;

        // ---- 5. qk_h[e=lane] = sum_{d in head h} qd[d]*Wk[e][d]  (batched)
        {
            float qk0[4] = {0.f,0.f,0.f,0.f}, qk1[4] = {0.f,0.f,0.f,0.f};
            #pragma unroll
            for (int hh = 0; hh < 4; ++hh) {
                #pragma unroll
                for (int c4 = 0; c4 < 4; ++c4) {
                    const float4 k4 = *(const float4*)&Wk[wof + hh * 16 + c4 * 4];
                    const float4 a0 = *(float4*)&xb[w][0][hh * 16 + c4 * 4];
                    const float4 a1 = *(float4*)&xb[w][1][hh * 16 + c4 * 4];
                    qk0[hh] += a0.x*k4.x + a0.y*k4.y + a0.z*k4.z + a0.w*k4.w;
                    qk1[hh] += a1.x*k4.x + a1.y*k4.y + a1.z*k4.z + a1.w*k4.w;
                }
            }
            #pragma unroll
            for (int hh = 0; hh < 4; ++hh) {
                qz[w][0][hh][lane] = qk0[hh];
                qz[w][1][hh][lane] = qk1[hh];
            }
        }

        // ---- 6. per-pair: scores -> softmax -> z
        #pragma unroll
        for (int q = 0; q < 2; ++q) {
            const float4 myqk = *(float4*)&qz[w][q][h][c * 4];
            float sc[K];
            #pragma unroll
            for (int j = 0; j < K; ++j) {
                const float4 kk = *(float4*)&kin[w][q][j][c * 4];
                sc[j] = myqk.x*kk.x + myqk.y*kk.y + myqk.z*kk.z + myqk.w*kk.w;
            }
            #pragma unroll
            for (int off = 1; off < 16; off <<= 1) {
                #pragma unroll
                for (int j = 0; j < K; ++j) sc[j] += __shfl_xor(sc[j], off, 16);
            }
            #pragma unroll
            for (int j = 0; j < K; ++j) {
                float s = sc[j] * 0.25f;                // 1/sqrt(16)
                if ((mb[q] >> j) & 1) s = -1e9f;
                sc[j] = s;
            }
            float mx = sc[0];
            #pragma unroll
            for (int j = 1; j < K; ++j) mx = fmaxf(mx, sc[j]);
            float sum = 0.0f;
            #pragma unroll
            for (int j = 0; j < K; ++j) { sc[j] = __expf(sc[j] - mx); sum += sc[j]; }
            const float inv = 1.0f / sum;
            float zx = 0.f, zy = 0.f, zz = 0.f, zw = 0.f;
            #pragma unroll
            for (int j = 0; j < K; ++j) {
                const float4 kk = *(float4*)&kin[w][q][j][c * 4];
                zx += sc[j]*kk.x; zy += sc[j]*kk.y; zz += sc[j]*kk.z; zw += sc[j]*kk.w;
            }
            float4 z4; z4.x = zx*inv; z4.y = zy*inv; z4.z = zz*inv; z4.w = zw*inv;
            *(float4*)&qz[w][q][h][c * 4] = z4;
        }

        // ---- 7. od[d=lane] = sum_e z_h(d)[e]*Wv[e][d]  (batched)
        float od0 = 0.f, od1 = 0.f;
        #pragma unroll
        for (int e4 = 0; e4 < 16; ++e4) {
            const float4 wv4 = *(const float4*)&WvT[wof + e4 * 4];
            const float4 z0  = *(float4*)&qz[w][0][h][e4 * 4];
            const float4 z1  = *(float4*)&qz[w][1][h][e4 * 4];
            od0 += z0.x*wv4.x + z0.y*wv4.y + z0.z*wv4.z + z0.w*wv4.w;
            od1 += z1.x*wv4.x + z1.y*wv4.y + z1.z*wv4.z + z1.w*wv4.w;
        }
        xb[w][0][lane] = od0;
        xb[w][1][lane] = od1;

        // ---- 8. o2 = od @ Wo  (batched); write into merge concat buffer
        float o20 = 0.f, o21 = 0.f;
        #pragma unroll
        for (int e4 = 0; e4 < 16; ++e4) {
            const float4 wo4 = *(const float4*)&WoT[wof + e4 * 4];
            const float4 x0  = *(float4*)&xb[w][0][e4 * 4];
            const float4 x1  = *(float4*)&xb[w][1][e4 * 4];
            o20 += x0.x*wo4.x + x0.y*wo4.y + x0.z*wo4.z + x0.w*wo4.w;
            o21 += x1.x*wo4.x + x1.y*wo4.y + x1.z*wo4.z + x1.w*wo4.w;
        }
        float* mx0 = &qz[w][0][0][0];   // qz dead after step 7: alias as concat[96]
        float* mx1 = &qz[w][1][0][0];
        mx0[lane] = o20;
        mx1[lane] = o21;
        if (lane < 32) {
            mx0[64 + lane] = qin[w][0][lane];
            mx1[64 + lane] = qin[w][1][lane];
        }

        // ---- 9. merge layer 1 (batched, half-split over e-range)
        const int dd = td;
        float hv0 = 0.f, hv1 = 0.f;
        #pragma unroll
        for (int e4 = 0; e4 < 12; ++e4) {
            const float4 w4 = *(const float4*)&mw1T[dd * 96 + half * 48 + e4 * 4];
            const float4 x0 = *(float4*)&mx0[half * 48 + e4 * 4];
            const float4 x1 = *(float4*)&mx1[half * 48 + e4 * 4];
            hv0 += x0.x*w4.x + x0.y*w4.y + x0.z*w4.z + x0.w*w4.w;
            hv1 += x1.x*w4.x + x1.y*w4.y + x1.z*w4.z + x1.w*w4.w;
        }
        hv0 += __shfl_xor(hv0, 32);
        hv1 += __shfl_xor(hv1, 32);
        hv0 = fmaxf(hv0 + mb1[dd], 0.0f);
        hv1 = fmaxf(hv1 + mb1[dd], 0.0f);
        if (lane < 32) { xb[w][0][dd] = hv0; xb[w][1][dd] = hv1; }

        // ---- 10. merge layer 2 + store
        float y0 = 0.f, y1 = 0.f;
        #pragma unroll
        for (int e4 = 0; e4 < 4; ++e4) {
            const float4 w4 = *(const float4*)&mw2T[dd * 32 + half * 16 + e4 * 4];
            const float4 x0 = *(float4*)&xb[w][0][half * 16 + e4 * 4];
            const float4 x1 = *(float4*)&xb[w][1][half * 16 + e4 * 4];
            y0 += x0.x*w4.x + x0.y*w4.y + x0.z*w4.z + x0.w*w4.w;
            y1 += x1.x*w4.x + x1.y*w4.y + x1.z*w4.z + x1.w*w4.w;
        }
        y0 += __shfl_xor(y0, 32);
        y1 += __shfl_xor(y1, 32);
        if (lane < 32) {
            #pragma unroll
            for (int q = 0; q < 2; ++q) {
                const int i    = gs * 2 + q;
                const int side = (i >= NPAIRS) ? 1 : 0;
                const int p    = i - side * NPAIRS;
                const float y  = (q == 0) ? y0 : y1;
                h_out[((size_t)side * NPAIRS + p) * F + dd] = y + mb2[dd];
            }
        }
    }
}

__global__ __launch_bounds__(256) void final_kernel(
    const float* __restrict__ h3,
    const float* __restrict__ aw1, const float* __restrict__ ab1,
    const float* __restrict__ aw2, const float* __restrict__ ab2,
    float* __restrict__ out)
{
    const int bidx = threadIdx.x;   // 256 threads, 1 block
    float x[64];
    #pragma unroll
    for (int e = 0; e < 32; ++e) {
        x[e]      = h3[(size_t)bidx * 32 + e];
        x[32 + e] = h3[((size_t)NP3 + bidx) * 32 + e];
    }
    float acc = ab2[0];
    for (int f = 0; f < 32; ++f) {
        float hv = ab1[f];
        #pragma unroll
        for (int e = 0; e < 64; ++e) hv += x[e] * aw1[e * 32 + f];
        acc += fmaxf(hv, 0.0f) * aw2[f];
    }
    out[bidx] = acc;
}

extern "C" void kernel_launch(void* const* d_in, const int* in_sizes, int n_in,
                              void* d_out, int out_size, void* d_ws, size_t ws_size,
                              hipStream_t stream)
{
    const int*   src_idx = (const int*)d_in[0];
    const int*   tgt_idx = (const int*)d_in[1];
    const float* cut     = (const float*)d_in[2];
    const float* emb   = (const float*)d_in[4];
    const float* freq  = (const float*)d_in[5];
    const float* phase = (const float*)d_in[6];
    const float* Wq    = (const float*)d_in[7];
    const float* Wk    = (const float*)d_in[8];
    const float* Wv    = (const float*)d_in[9];
    const float* Wo    = (const float*)d_in[10];
    const float* mw1   = (const float*)d_in[11];
    const float* mb1   = (const float*)d_in[12];
    const float* mw2   = (const float*)d_in[13];
    const float* mb2   = (const float*)d_in[14];
    const float* aw1   = (const float*)d_in[15];
    const float* ab1   = (const float*)d_in[16];
    const float* aw2   = (const float*)d_in[17];
    const float* ab2   = (const float*)d_in[18];

    float* ws = (float*)d_ws;
    const float* WqT  = ws + OFF_WQT;
    const float* WvT  = ws + OFF_WVT;
    const float* WoT  = ws + OFF_WOT;
    const float* mw1T = ws + OFF_MW1T;
    const float* mw2T = ws + OFF_MW2T;
    float* h1 = ws + OFF_H1;
    float* h2 = ws + OFF_H2;
    float* h3 = ws + OFF_H3;

    const dim3 blk(256);
    transpose_weights<<<dim3(3), blk, 0, stream>>>(Wq, Wv, Wo, mw1, mw2, ws);
    // 3 blocks/CU (LDS 53.7KB) x 256 CU = 768 persistent blocks
    attn_kernel<1><<<dim3(768), blk, 0, stream>>>(
        src_idx, tgt_idx, cut, emb, freq, phase,
        Wk, WqT, WvT, WoT, mw1T, mb1, mw2T, mb2, (const float*)nullptr, h1);
    attn_kernel<2><<<dim3(768), blk, 0, stream>>>(
        src_idx, tgt_idx, cut, emb, freq, phase,
        Wk, WqT, WvT, WoT, mw1T, mb1, mw2T, mb2, h1, h2);
    attn_kernel<3><<<dim3(64), blk, 0, stream>>>(
        src_idx, tgt_idx, cut, emb, freq, phase,
        Wk, WqT, WvT, WoT, mw1T, mb1, mw2T, mb2, h2, h3);
    final_kernel<<<dim3(1), blk, 0, stream>>>(h3, aw1, ab1, aw2, ab2, (float*)d_out);
}

// Round 4
// 815.724 us; speedup vs baseline: 2.9835x; 2.9835x over previous
//
#include <hip/hip_runtime.h>
#include <math.h>

#define K 20
#define KP1 21
#define F 32
#define NNODES 1000000

#define NP1 112896   // 5376*21
#define NP2 5376     // 256*21
#define NP3 256

// ws float offsets: 3 contiguous per-layer weight blocks of 16640 floats:
//   +0     M[a][e][h]   (32*64*4 = 8192)
//   +8192  C[e][h]      (256)
//   +8448  WvT[d][e]    (4096)
//   +12544 PcT[f][k96]  (3072)   Pcat = [Wo@mw1A ; mw1B] transposed
//   +15616 mw2T[d][e]   (1024)
#define WBLK 16640
#define OFF_H1 49920
#define OFF_H2 (OFF_H1 + 2 * NP1 * F)
#define OFF_H3 (OFF_H2 + 2 * NP2 * F)

// LDS float offsets (per block, dynamic smem)
#define LDS_M    0
#define LDS_C    8192
#define LDS_WVT  8448    // stride 68
#define LDS_PCT  12800   // stride 100
#define LDS_M2   16000   // stride 36
#define LDS_WAVE 17152   // + w*1648 : kin 1280 | qf 32 | qz 272 ([h*68+e]) | ob 64
#define WV_STRIDE 1648
#define SMEM_FLOATS (LDS_WAVE + 12 * WV_STRIDE)   // 36928 floats = 147712 B

__device__ __forceinline__ int nhash(int node, int j) {
    return (node * 101 + (j + 1) * 7919) % NNODES;   // max ~1.01e8, fits int32
}

__global__ __launch_bounds__(256) void transform_weights(
    const float* __restrict__ Wq, const float* __restrict__ Wk,
    const float* __restrict__ Wv, const float* __restrict__ Wo,
    const float* __restrict__ mw1, const float* __restrict__ mw2,
    const float* __restrict__ phase, float* __restrict__ ws)
{
    const int l = blockIdx.x, tid = threadIdx.x;
    const float* wq = Wq + l * 4096; const float* wk = Wk + l * 4096;
    const float* wv = Wv + l * 4096; const float* wo = Wo + l * 4096;
    const float* m1 = mw1 + l * 3072; const float* m2 = mw2 + l * 1024;
    float* out = ws + l * WBLK;
    // M[a][e][h] = sum_{d in head h} Wq[a][d] * Wk[e][d]
    for (int i = tid; i < 8192; i += 256) {
        const int a = i >> 8, e = (i >> 2) & 63, h = i & 3;
        float s = 0.f;
        for (int t = 0; t < 16; ++t) s += wq[a * 64 + h * 16 + t] * wk[e * 64 + h * 16 + t];
        out[i] = s;
    }
    // C[e][h] = sum_{a time} cos(phase[a]) * M_time[a][e][h]
    for (int i = tid; i < 256; i += 256) {
        const int e = i >> 2, h = i & 3;
        float s = 0.f;
        for (int a = 0; a < 32; ++a) {
            float acc = 0.f;
            for (int t = 0; t < 16; ++t) acc += wq[(32 + a) * 64 + h * 16 + t] * wk[e * 64 + h * 16 + t];
            s += cosf(phase[a]) * acc;
        }
        out[8192 + i] = s;
    }
    // WvT[d][e] = Wv[e][d]
    for (int i = tid; i < 4096; i += 256) { const int d = i >> 6, e = i & 63; out[8448 + i] = wv[e * 64 + d]; }
    // PcT[f][k]: k<64 -> (Wo@mw1A)[k][f]; k>=64 -> mw1[k][f]
    for (int i = tid; i < 3072; i += 256) {
        const int f = i / 96, k = i - f * 96;
        float v;
        if (k < 64) { v = 0.f; for (int g2 = 0; g2 < 64; ++g2) v += wo[k * 64 + g2] * m1[g2 * 32 + f]; }
        else v = m1[k * 32 + f];
        out[12544 + i] = v;
    }
    // mw2T[d][e]
    for (int i = tid; i < 1024; i += 256) { const int d = i >> 5, e = i & 31; out[15616 + i] = m2[e * 32 + d]; }
}

template<int LEVEL>
__global__ __launch_bounds__(768) void attn_kernel(
    const int* __restrict__ src_idx, const int* __restrict__ tgt_idx,
    const float* __restrict__ cut_time, const float* __restrict__ emb,
    const float* __restrict__ freq, const float* __restrict__ phase,
    const float* __restrict__ ws_w,
    const float* __restrict__ mb1_, const float* __restrict__ mb2_,
    const float* __restrict__ h_in, float* __restrict__ h_out)
{
    constexpr int NPAIRS = (LEVEL == 1) ? NP1 : (LEVEL == 2 ? NP2 : NP3);
    constexpr int PREVN  = (LEVEL == 2) ? NP1 : NP2;
    constexpr int l = LEVEL - 1;

    extern __shared__ float smem[];

    const int tid  = threadIdx.x;
    const int w    = tid >> 6;
    const int lane = tid & 63;
    const int h    = lane >> 4;
    const int c3   = lane & 7;
    const int rep  = (lane >> 3) & 1;
    const int td   = lane & 31;
    const int half = lane >> 5;

    // ---- stage weights into LDS once per block
    {
        const float* wsrc = ws_w + l * WBLK;
        for (int i4 = tid; i4 < 2112; i4 += 768)           // M + C (float4)
            *(float4*)&smem[i4 * 4] = *(const float4*)&wsrc[i4 * 4];
        for (int i = tid; i < 4096; i += 768) { const int d = i >> 6, e = i & 63; smem[LDS_WVT + d * 68 + e] = wsrc[8448 + i]; }
        for (int i = tid; i < 3072; i += 768) { const int f = i / 96, k = i - f * 96; smem[LDS_PCT + f * 100 + k] = wsrc[12544 + i]; }
        for (int i = tid; i < 1024; i += 768) { const int d = i >> 5, e = i & 31; smem[LDS_M2 + d * 36 + e] = wsrc[15616 + i]; }
    }
    __syncthreads();

    float* sM   = smem;
    float* sC   = smem + LDS_C;
    float* sWvT = smem + LDS_WVT;
    float* sPcT = smem + LDS_PCT;
    float* sm2  = smem + LDS_M2;
    float* kin  = smem + LDS_WAVE + w * WV_STRIDE;   // [j*64 + e]
    float* qfb  = kin + 1280;                        // [32]
    float* qzb  = kin + 1312;                        // [h*68 + e]
    float* obb  = kin + 1584;                        // [64]

    const float fr = freq[td], ph = phase[td];
    const float b1v = mb1_[l * 32 + td], b2v = mb2_[l * 32 + td];

    const int gstride = gridDim.x * 12;
    float4 pf0, pf1, pf2; int na; float ta;

    auto PRE = [&](int i) {
        const int side = (i >= NPAIRS) ? 1 : 0;
        const int p = i - side * NPAIRS;
        int b, s2 = 0, r = 0;
        if (LEVEL == 3)      { b = p; }
        else if (LEVEL == 2) { b = p / KP1; s2 = p % KP1; }
        else                 { int qq = p / KP1; r = p % KP1; b = qq / KP1; s2 = qq % KP1; }
        const int root = side ? tgt_idx[b] : src_idx[b];
        const float ct = cut_time[b];
        if (LEVEL == 3) { na = root; ta = ct; }
        else if (LEVEL == 2) {
            na = s2 ? nhash(root, s2 - 1) : root;
            ta = s2 ? ct * ((float)s2 / 21.0f) : ct;
        } else {
            const int   n2 = s2 ? nhash(root, s2 - 1) : root;
            const float t2 = s2 ? ct * ((float)s2 / 21.0f) : ct;
            na = r ? nhash(n2, r - 1) : n2;
            ta = r ? t2 * ((float)r / 21.0f) : t2;
        }
        if (LEVEL == 1) {
            { const int row = lane >> 3, c4 = lane & 7;
              const int node = row ? nhash(na, row - 1) : na;
              pf0 = *(const float4*)&emb[(size_t)node * F + c4 * 4]; }
            { const int idx4 = 64 + lane, row = idx4 >> 3, c4 = idx4 & 7;
              const int node = nhash(na, row - 1);
              pf1 = *(const float4*)&emb[(size_t)node * F + c4 * 4]; }
            { const int idx4 = 128 + lane;
              if (idx4 < 168) {
                  const int row = idx4 >> 3, c4 = idx4 & 7;
                  const int node = nhash(na, row - 1);
                  pf2 = *(const float4*)&emb[(size_t)node * F + c4 * 4]; } }
        } else {
            const float* base = h_in + ((size_t)side * PREVN + (size_t)p * KP1) * F;
            pf0 = *(const float4*)&base[lane * 4];
            pf1 = *(const float4*)&base[(64 + lane) * 4];
            if (128 + lane < 168) pf2 = *(const float4*)&base[(128 + lane) * 4];
        }
    };

    int g = blockIdx.x * 12 + w;
    if (g < 2 * NPAIRS) PRE(g);

    for (; g < 2 * NPAIRS; g += gstride) {
        const int curside = (g >= NPAIRS) ? 1 : 0;
        const int curp = g - curside * NPAIRS;
        const int   cna = na;
        const float cta = ta;

        // ---- fill LDS from prefetch regs
        { const int row = lane >> 3, c4 = lane & 7;
          if (row == 0) *(float4*)&qfb[c4 * 4] = pf0;
          else          *(float4*)&kin[(row - 1) * 64 + c4 * 4] = pf0; }
        { const int idx4 = 64 + lane, row = idx4 >> 3, c4 = idx4 & 7;
          *(float4*)&kin[(row - 1) * 64 + c4 * 4] = pf1; }
        { const int idx4 = 128 + lane;
          if (idx4 < 168) { const int row = idx4 >> 3, c4 = idx4 & 7;
            *(float4*)&kin[(row - 1) * 64 + c4 * 4] = pf2; } }

        // ---- time encodings (2 j's per iteration across halves)
        #pragma unroll
        for (int it = 0; it < 10; ++it) {
            const int j = it * 2 + half;
            const float ngh_t = cta * ((float)(j + 1) / 21.0f);
            const float delta = cta - ngh_t;
            kin[j * 64 + 32 + td] = cosf(delta * fr + ph);
        }
        // ---- mask bits (incremental mod)
        unsigned mbits = 0;
        { int m = (cna * 101 + 7919) % NNODES;
          #pragma unroll
          for (int j = 0; j < K; ++j) {
              if (m == 0) mbits |= (1u << j);
              m += 7919; if (m >= NNODES) m -= NNODES;
          } }

        if (g + gstride < 2 * NPAIRS) PRE(g + gstride);

        // ---- QK phase: lane = e; qk_h[e] = C[e][h] + sum_a feat[a]*M[a][e][h]
        float4 acc = *(const float4*)&sC[lane * 4];
        #pragma unroll
        for (int a4 = 0; a4 < 8; ++a4) {
            const float4 f4 = *(float4*)&qfb[a4 * 4];
            const float4 m0 = *(const float4*)&sM[(a4 * 4 + 0) * 256 + lane * 4];
            const float4 m1v = *(const float4*)&sM[(a4 * 4 + 1) * 256 + lane * 4];
            const float4 m2v = *(const float4*)&sM[(a4 * 4 + 2) * 256 + lane * 4];
            const float4 m3 = *(const float4*)&sM[(a4 * 4 + 3) * 256 + lane * 4];
            acc.x += f4.x * m0.x + f4.y * m1v.x + f4.z * m2v.x + f4.w * m3.x;
            acc.y += f4.x * m0.y + f4.y * m1v.y + f4.z * m2v.y + f4.w * m3.y;
            acc.z += f4.x * m0.z + f4.y * m1v.z + f4.z * m2v.z + f4.w * m3.z;
            acc.w += f4.x * m0.w + f4.y * m1v.w + f4.z * m2v.w + f4.w * m3.w;
        }
        qzb[0 * 68 + lane] = acc.x; qzb[1 * 68 + lane] = acc.y;
        qzb[2 * 68 + lane] = acc.z; qzb[3 * 68 + lane] = acc.w;

        // ---- scores: lane=(h,rep,c3); 8-e slice, 10 j's per rep-half
        const float4 qk0 = *(float4*)&qzb[h * 68 + c3 * 8];
        const float4 qk1 = *(float4*)&qzb[h * 68 + c3 * 8 + 4];
        const int j0 = rep * 10;
        float sc[10];
        #pragma unroll
        for (int t = 0; t < 10; ++t) {
            const float4 k0 = *(float4*)&kin[(j0 + t) * 64 + c3 * 8];
            const float4 k1 = *(float4*)&kin[(j0 + t) * 64 + c3 * 8 + 4];
            sc[t] = qk0.x * k0.x + qk0.y * k0.y + qk0.z * k0.z + qk0.w * k0.w
                  + qk1.x * k1.x + qk1.y * k1.y + qk1.z * k1.z + qk1.w * k1.w;
        }
        #pragma unroll
        for (int off = 1; off < 8; off <<= 1) {
            #pragma unroll
            for (int t = 0; t < 10; ++t) sc[t] += __shfl_xor(sc[t], off, 8);
        }
        #pragma unroll
        for (int t = 0; t < 10; ++t) {
            float s = sc[t] * 0.25f;                      // 1/sqrt(16)
            if ((mbits >> (j0 + t)) & 1) s = -1e9f;
            sc[t] = s;
        }
        float mx = sc[0];
        #pragma unroll
        for (int t = 1; t < 10; ++t) mx = fmaxf(mx, sc[t]);
        mx = fmaxf(mx, __shfl_xor(mx, 8, 16));
        float sum = 0.f;
        #pragma unroll
        for (int t = 0; t < 10; ++t) { sc[t] = __expf(sc[t] - mx); sum += sc[t]; }
        sum += __shfl_xor(sum, 8, 16);
        const float inv = 1.0f / sum;
        // z partials over my 10 j's, then rep-exchange
        float4 z0 = {0, 0, 0, 0}, z1 = {0, 0, 0, 0};
        #pragma unroll
        for (int t = 0; t < 10; ++t) {
            const float4 k0 = *(float4*)&kin[(j0 + t) * 64 + c3 * 8];
            const float4 k1 = *(float4*)&kin[(j0 + t) * 64 + c3 * 8 + 4];
            z0.x += sc[t] * k0.x; z0.y += sc[t] * k0.y; z0.z += sc[t] * k0.z; z0.w += sc[t] * k0.w;
            z1.x += sc[t] * k1.x; z1.y += sc[t] * k1.y; z1.z += sc[t] * k1.z; z1.w += sc[t] * k1.w;
        }
        z0.x += __shfl_xor(z0.x, 8, 16); z0.y += __shfl_xor(z0.y, 8, 16);
        z0.z += __shfl_xor(z0.z, 8, 16); z0.w += __shfl_xor(z0.w, 8, 16);
        z1.x += __shfl_xor(z1.x, 8, 16); z1.y += __shfl_xor(z1.y, 8, 16);
        z1.z += __shfl_xor(z1.z, 8, 16); z1.w += __shfl_xor(z1.w, 8, 16);
        z0.x *= inv; z0.y *= inv; z0.z *= inv; z0.w *= inv;
        z1.x *= inv; z1.y *= inv; z1.z *= inv; z1.w *= inv;
        if (rep == 0) {
            *(float4*)&qzb[h * 68 + c3 * 8] = z0;
            *(float4*)&qzb[h * 68 + c3 * 8 + 4] = z1;
        }

        // ---- OD: lane = d; od = sum_e z_{h(d)}[e] * Wv[e][d]
        float od = 0.f;
        #pragma unroll
        for (int e4 = 0; e4 < 16; ++e4) {
            const float4 z  = *(float4*)&qzb[h * 68 + e4 * 4];
            const float4 wv = *(float4*)&sWvT[lane * 68 + e4 * 4];
            od += z.x * wv.x + z.y * wv.y + z.z * wv.z + z.w * wv.w;
        }
        obb[lane] = od;

        // ---- merge1 via Pcat: hv[f] = [od||feat] @ Pcat[:,f]
        float hv = 0.f;
        #pragma unroll
        for (int e4 = 0; e4 < 12; ++e4) {
            float4 x;
            if (half == 0) x = *(float4*)&obb[e4 * 4];
            else x = (e4 < 4) ? *(float4*)&obb[48 + e4 * 4]
                              : *(float4*)&qfb[(e4 - 4) * 4];
            const float4 w4 = *(float4*)&sPcT[td * 100 + half * 48 + e4 * 4];
            hv += x.x * w4.x + x.y * w4.y + x.z * w4.z + x.w * w4.w;
        }
        hv += __shfl_xor(hv, 32);
        hv = fmaxf(hv + b1v, 0.0f);
        if (lane < 32) obb[td] = hv;     // alias hidden buffer onto obb[0..31]

        // ---- merge2 + store
        float y = 0.f;
        #pragma unroll
        for (int e4 = 0; e4 < 4; ++e4) {
            const float4 x  = *(float4*)&obb[half * 16 + e4 * 4];
            const float4 w4 = *(float4*)&sm2[td * 36 + half * 16 + e4 * 4];
            y += x.x * w4.x + x.y * w4.y + x.z * w4.z + x.w * w4.w;
        }
        y += __shfl_xor(y, 32);
        if (lane < 32)
            h_out[((size_t)curside * NPAIRS + curp) * F + td] = y + b2v;
    }
}

__global__ __launch_bounds__(256) void final_kernel(
    const float* __restrict__ h3,
    const float* __restrict__ aw1, const float* __restrict__ ab1,
    const float* __restrict__ aw2, const float* __restrict__ ab2,
    float* __restrict__ out)
{
    const int bidx = threadIdx.x;   // 256 threads, 1 block
    float x[64];
    #pragma unroll
    for (int e = 0; e < 32; ++e) {
        x[e]      = h3[(size_t)bidx * 32 + e];
        x[32 + e] = h3[((size_t)NP3 + bidx) * 32 + e];
    }
    float acc = ab2[0];
    for (int f = 0; f < 32; ++f) {
        float hv = ab1[f];
        #pragma unroll
        for (int e = 0; e < 64; ++e) hv += x[e] * aw1[e * 32 + f];
        acc += fmaxf(hv, 0.0f) * aw2[f];
    }
    out[bidx] = acc;
}

extern "C" void kernel_launch(void* const* d_in, const int* in_sizes, int n_in,
                              void* d_out, int out_size, void* d_ws, size_t ws_size,
                              hipStream_t stream)
{
    const int*   src_idx = (const int*)d_in[0];
    const int*   tgt_idx = (const int*)d_in[1];
    const float* cut     = (const float*)d_in[2];
    const float* emb   = (const float*)d_in[4];
    const float* freq  = (const float*)d_in[5];
    const float* phase = (const float*)d_in[6];
    const float* Wq    = (const float*)d_in[7];
    const float* Wk    = (const float*)d_in[8];
    const float* Wv    = (const float*)d_in[9];
    const float* Wo    = (const float*)d_in[10];
    const float* mw1   = (const float*)d_in[11];
    const float* mb1   = (const float*)d_in[12];
    const float* mw2   = (const float*)d_in[13];
    const float* mb2   = (const float*)d_in[14];
    const float* aw1   = (const float*)d_in[15];
    const float* ab1   = (const float*)d_in[16];
    const float* aw2   = (const float*)d_in[17];
    const float* ab2   = (const float*)d_in[18];

    float* ws = (float*)d_ws;
    float* h1 = ws + OFF_H1;
    float* h2 = ws + OFF_H2;
    float* h3 = ws + OFF_H3;

    const size_t smem_bytes = SMEM_FLOATS * sizeof(float);
    hipFuncSetAttribute((const void*)attn_kernel<1>, hipFuncAttributeMaxDynamicSharedMemorySize, (int)smem_bytes);
    hipFuncSetAttribute((const void*)attn_kernel<2>, hipFuncAttributeMaxDynamicSharedMemorySize, (int)smem_bytes);
    hipFuncSetAttribute((const void*)attn_kernel<3>, hipFuncAttributeMaxDynamicSharedMemorySize, (int)smem_bytes);

    transform_weights<<<dim3(3), dim3(256), 0, stream>>>(Wq, Wk, Wv, Wo, mw1, mw2, phase, ws);
    attn_kernel<1><<<dim3(256), dim3(768), smem_bytes, stream>>>(
        src_idx, tgt_idx, cut, emb, freq, phase, ws, mb1, mb2, (const float*)nullptr, h1);
    attn_kernel<2><<<dim3(256), dim3(768), smem_bytes, stream>>>(
        src_idx, tgt_idx, cut, emb, freq, phase, ws, mb1, mb2, h1, h2);
    attn_kernel<3><<<dim3(64), dim3(768), smem_bytes, stream>>>(
        src_idx, tgt_idx, cut, emb, freq, phase, ws, mb1, mb2, h2, h3);
    final_kernel<<<dim3(1), dim3(256), 0, stream>>>(h3, aw1, ab1, aw2, ab2, (float*)d_out);
}